// Round 14
// baseline (28493.414 us; speedup 1.0000x reference)
//
#include <hip/hip_runtime.h>

#define KK 67
#define DIN 4
#define CLIPM 16
#define NEPOCH 5

typedef _Float16 half2v __attribute__((ext_vector_type(2)));
typedef __fp16  fp16v2 __attribute__((ext_vector_type(2)));

__device__ __forceinline__ float ex2(float x) {
#if __has_builtin(__builtin_amdgcn_exp2f)
    return __builtin_amdgcn_exp2f(x);
#else
    return exp2f(x);
#endif
}
__device__ __forceinline__ float frcp(float x) {
#if __has_builtin(__builtin_amdgcn_rcpf)
    return __builtin_amdgcn_rcpf(x);
#else
    return 1.0f / x;
#endif
}
__device__ __forceinline__ float pkrtzf(float a, float b) {
    return __builtin_bit_cast(float, __builtin_amdgcn_cvt_pkrtz(a, b));
}
// v_dot2_f32_f16: d = a.lo*b.lo + a.hi*b.hi + c (f32 accumulate)
__device__ __forceinline__ float fdot2(float a_bits, half2v b, float c) {
#if __has_builtin(__builtin_amdgcn_fdot2)
    return __builtin_amdgcn_fdot2(__builtin_bit_cast(fp16v2, a_bits),
                                  __builtin_bit_cast(fp16v2, b), c, false);
#else
    half2v a = __builtin_bit_cast(half2v, a_bits);
    return (float)a.x * (float)b.x + (float)a.y * (float)b.y + c;
#endif
}
// DPP: 0x128 = row_ror:8 (within 16-lane row)
template<int CTRL>
__device__ __forceinline__ float dppf(float v) {
    return __int_as_float(__builtin_amdgcn_mov_dpp(__float_as_int(v), CTRL, 0xF, 0xF, false));
}
// ds_swizzle BitMode: offset = (xor<<10) | 0x1F (within 32-lane group)
template<int PAT>
__device__ __forceinline__ float swzf(float v) {
    return __int_as_float(__builtin_amdgcn_ds_swizzle(__float_as_int(v), PAT));
}
// broadcast lane n of v to all lanes (SGPR result)
template<int LN>
__device__ __forceinline__ float rdlane(float v) {
    return __int_as_float(__builtin_amdgcn_readlane(__float_as_int(v), LN));
}

// ---------------- Phase 1: per-frame GRNN + projections (parallel over T) ----------------
__global__ __launch_bounds__(128) void grnn_kernel(
    const float* __restrict__ vid,
    const float* __restrict__ W1, const float* __restrict__ b1,
    const float* __restrict__ gw, const float* __restrict__ gb,
    const float* __restrict__ gWih, const float* __restrict__ gWhh,
    const float* __restrict__ gbih, const float* __restrict__ gbhh,
    const float* __restrict__ W2, const float* __restrict__ b2,
    float* __restrict__ q)
{
    const int f = blockIdx.x;
    const int t = threadIdx.x;
    const int k = t;
    __shared__ float sWih[256], sWhh[256], sb[32], sW1[32], sb1[8], sW2[64], sb2[8];
    __shared__ float Msum[8];
    for (int i = t; i < 256; i += 128) { sWih[i] = gWih[i]; sWhh[i] = gWhh[i]; }
    if (t < 32) sb[t] = gbih[t] + gbhh[t];
    if (t < 32) sW1[t] = W1[t];
    if (t < 8)  sb1[t] = b1[t];
    if (t < 64) sW2[t] = W2[t];
    if (t < 8)  sb2[t] = b2[t];
    __syncthreads();

    const bool act = (k < KK);
    float R[8], S[8], gwl[8], gbl[8];
    if (act) {
        const float* vp = vid + ((size_t)f * KK + k) * DIN;
        const float v0 = vp[0], v1 = vp[1], v2 = vp[2], v3 = vp[3];
#pragma unroll
        for (int j = 0; j < 8; ++j) {
            R[j] = sb1[j] + sW1[j*4+0]*v0 + sW1[j*4+1]*v1 + sW1[j*4+2]*v2 + sW1[j*4+3]*v3;
            S[j] = 0.0f;
            gwl[j] = gw[k*8 + j];
            gbl[j] = gb[k*8 + j];
        }
    }
    for (int e = 0; e < NEPOCH; ++e) {
        if (t < 8) Msum[t] = 0.0f;
        __syncthreads();
        float per[8];
        if (act) {
#pragma unroll
            for (int j = 0; j < 8; ++j) { per[j] = gwl[j]*S[j] + gbl[j]; atomicAdd(&Msum[j], per[j]); }
        }
        __syncthreads();
        if (act) {
            float M[8];
#pragma unroll
            for (int j = 0; j < 8; ++j) M[j] = Msum[j] - per[j];
            float gv[32];
#pragma unroll
            for (int gg = 0; gg < 32; ++gg) {
                float a = sb[gg];
#pragma unroll
                for (int j = 0; j < 8; ++j)
                    a = fmaf(R[j], sWih[gg*8+j], fmaf(M[j], sWhh[gg*8+j], a));
                gv[gg] = a;
            }
#pragma unroll
            for (int j = 0; j < 8; ++j) {
                float sg_i = frcp(1.f + ex2(-1.4426950408889634f * gv[j]));
                float sg_f = frcp(1.f + ex2(-1.4426950408889634f * gv[8+j]));
                float th_g = 1.f - 2.f * frcp(1.f + ex2(2.8853900817779268f * gv[16+j]));
                float sg_o = frcp(1.f + ex2(-1.4426950408889634f * gv[24+j]));
                float c2 = sg_f * S[j] + sg_i * th_g;
                float h2 = sg_o * (1.f - 2.f * frcp(1.f + ex2(2.8853900817779268f * c2)));
                R[j] += S[j];   // updateRelation uses OLD lastS
                S[j] = h2;
            }
        }
        __syncthreads();
    }
    if (act) {
        float* qp = q + ((size_t)f * KK + k) * 8;
#pragma unroll
        for (int jo = 0; jo < 8; ++jo) {
            float a = sb2[jo];
#pragma unroll
            for (int j = 0; j < 8; ++j) a = fmaf(fmaxf(R[j], 0.0f), sW2[jo*8+j], a);
            qp[jo] = a;
        }
    }
}

// ---------------- Phase 2: layer-per-wave systolic, f32 h-recurrence ----------------
// 8 waves = 8 layers per chain; batch B=8 positions between __syncthreads.
// Wave l at interval I processes batch b=I-l from the y-batch wave l-1 wrote
// in interval I-1 (double-buffered LDS). Lane = gate row (i/f/g/o x 8 dims);
// x-side presummed with f16 dot2 (off the serial path); h-side is f32:
// 8 v_readlane broadcasts (no DS op in the recurrence) + 8 f32 FMAs.
__global__ void
__attribute__((amdgpu_flat_work_group_size(512, 512), amdgpu_waves_per_eu(2, 2)))
slstm_kernel(
    const float* __restrict__ q,
    const float* __restrict__ pWih, const float* __restrict__ pWhh,
    const float* __restrict__ pbih, const float* __restrict__ pbhh,
    const float* __restrict__ vWih, const float* __restrict__ vWhh,
    const float* __restrict__ vbih, const float* __restrict__ vbhh,
    float* __restrict__ out, int U, int N)
{
    const int tid  = threadIdx.x;
    const int l    = tid >> 6;          // wave index = layer
    const int lane = tid & 63;
    const int row  = lane & 31;         // gate row (i:0-7 f:8-15 g:16-23 o:24-31)
    const int isV  = blockIdx.x;
    const float* Wih = isV ? vWih : pWih;
    const float* Whh = isV ? vWhh : pWhh;
    const float* bi  = isV ? vbih : pbih;
    const float* bh  = isV ? vbhh : pbhh;
    float* ob = out + (size_t)isV * (size_t)N * 64;

    const float cS = -1.4426950408889634f;   // -log2(e): sigmoid rows
    const float cT =  2.8853900817779268f;   // 2*log2(e): tanh row
    const float invcT = 0.34657359027997264f;

    __shared__ float SB[9][2][128];

    // weights for row r: x-side f16 pairs, h-side f32 scalars
    half2v wx[4];
    float wh[8], bias;
    {
        const int r = l*32 + row;
        const float sc = ((row >> 3) == 2) ? cT : cS;
#pragma unroll
        for (int n = 0; n < 4; ++n)
            wx[n] = half2v{(_Float16)(sc * Wih[r*8 + 2*n]), (_Float16)(sc * Wih[r*8 + 2*n + 1])};
#pragma unroll
        for (int n = 0; n < 8; ++n)
            wh[n] = sc * Whh[r*8 + n];
        bias = sc * (bi[r] + bh[r]);
    }

    float cs = 0.f, Hm = 0.f, Hc = 0.f;
    float hs = 0.f;                     // h-state: lanes 0-7 hold dims 0-7
    int mb = 0, kclip = 0;
    const int NB = U / 8;
    const int t8 = lane >> 3, d8 = lane & 7;

    if (l == 0) SB[0][0][lane] = q[t8*8 + d8];   // stage batch 0 (u<8<KK)

    float qa_v = 0.f, qb_v = 0.f, msk = 0.f;
    const float vsel = isV ? 1.0f : 0.0f;

    for (int I = 0; I < NB + 7; ++I) {
        __syncthreads();
        const int b = I - l;
        if (b < 0 || b >= NB) continue;
        const int slot = b & 1;

        if (l == 0 && b + 1 < NB) {     // prefetch batch b+1
            const int ua = (b + 1)*8 + t8;
            qa_v = q[ua*8 + d8];
            int ub = ua - KK; if (ub < 0) ub = 0;
            qb_v = q[ub*8 + d8];
            msk = (ua >= KK) ? vsel : 0.f;
        }

        // batch-start: x-side gate pre-sums (f16 dot2, independent) + own x
        const float* sp = &SB[l][slot][0];
        float xacc[8], xf[8];
#pragma unroll
        for (int t = 0; t < 8; ++t) {
            const float4 ra  = *(const float4*)(sp + t*8);
            const float4 rb2 = *(const float4*)(sp + t*8 + 4);
            xf[t] = sp[t*8 + lane];
            const float p0 = pkrtzf(ra.x, ra.y);
            const float p1 = pkrtzf(ra.z, ra.w);
            const float p2 = pkrtzf(rb2.x, rb2.y);
            const float p3 = pkrtzf(rb2.z, rb2.w);
            float a = bias;
            a = fdot2(p0, wx[0], a);
            a = fdot2(p1, wx[1], a);
            a = fdot2(p2, wx[2], a);
            a = fdot2(p3, wx[3], a);
            xacc[t] = a;
        }
        float* wp = &SB[l+1][slot][0];

        const bool bnd = (mb == 133);
#pragma unroll
        for (int t = 0; t < 8; ++t) {
            // h broadcast via readlane (SGPRs) + f32 FMAs, two 4-chains
            const float s0 = rdlane<0>(hs), s1 = rdlane<1>(hs);
            const float s2 = rdlane<2>(hs), s3 = rdlane<3>(hs);
            const float s4 = rdlane<4>(hs), s5 = rdlane<5>(hs);
            const float s6 = rdlane<6>(hs), s7 = rdlane<7>(hs);
            float a1 = fmaf(s0, wh[0], xacc[t]);
            a1 = fmaf(s1, wh[1], a1);
            a1 = fmaf(s2, wh[2], a1);
            a1 = fmaf(s3, wh[3], a1);
            float a2 = s4 * wh[4];
            a2 = fmaf(s5, wh[5], a2);
            a2 = fmaf(s6, wh[6], a2);
            a2 = fmaf(s7, wh[7], a2);
            const float acc = a1 + a2;
            // one shared ex2; gather other gates' E from their rows
            const float E  = ex2(fminf(acc, 96.f));
            const float Ef = dppf<0x128>(E);        // row 8+d
            const float Eg = swzf<0x401F>(E);       // row 16+d
            const float Eo = swzf<0x601F>(E);       // row 24+d
            const float fg = frcp(1.f + Ef);
            const float ri = frcp((1.f + E) * (1.f + Eg));
            const float igtT = fmaf(cT, Eg, -cT) * ri;   // cT*ig*tanh(g)
            const float cs2 = fmaf(fg, cs, igtT);
            const float Ec = ex2(fminf(cs2, 96.f));
            const float rh = frcp((1.f + Ec) * (1.f + Eo));
            const float h2 = (Ec - 1.f) * rh;            // og*tanh(c), lanes 0-7 valid
            const float y = h2 + xf[t];
            wp[t*8 + lane] = y;
            if (bnd && t == 7) {
                const float c2 = cs2 * invcT;
                const float HmN = Hm + h2;
                const float HcN = Hc + c2;
                if (lane < 8) ob[(size_t)kclip * 64 + l*8 + lane] = HmN;
                Hm = HmN; Hc = HcN;
                cs = cT * HcN;
                hs = HmN;
            } else {
                cs = cs2;
                hs = h2;
            }
        }
        if (bnd) { mb = 0; ++kclip; } else { ++mb; }

        if (l == 0 && b + 1 < NB) {     // commit prefetched batch b+1
            SB[0][(b + 1) & 1][lane] = fmaf(-msk, qb_v, qa_v);
        }
    }
}

extern "C" void kernel_launch(void* const* d_in, const int* in_sizes, int n_in,
                              void* d_out, int out_size, void* d_ws, size_t ws_size,
                              hipStream_t stream)
{
    const float* vid  = (const float*)d_in[0];
    const float* W1   = (const float*)d_in[1];
    const float* b1   = (const float*)d_in[2];
    const float* gw   = (const float*)d_in[3];
    const float* gb   = (const float*)d_in[4];
    const float* gWih = (const float*)d_in[5];
    const float* gWhh = (const float*)d_in[6];
    const float* gbih = (const float*)d_in[7];
    const float* gbhh = (const float*)d_in[8];
    const float* W2   = (const float*)d_in[9];
    const float* b2   = (const float*)d_in[10];
    const float* vWih = (const float*)d_in[11];
    const float* vWhh = (const float*)d_in[12];
    const float* vbih = (const float*)d_in[13];
    const float* vbhh = (const float*)d_in[14];
    const float* pWih = (const float*)d_in[15];
    const float* pWhh = (const float*)d_in[16];
    const float* pbih = (const float*)d_in[17];
    const float* pbhh = (const float*)d_in[18];

    const int T = in_sizes[0] / (KK * DIN);
    const int N = T / CLIPM;
    const int U = N * CLIPM * KK;
    float* q = (float*)d_ws;   // T*KK*8 floats = 4.4 MB

    grnn_kernel<<<dim3(T), dim3(128), 0, stream>>>(
        vid, W1, b1, gw, gb, gWih, gWhh, gbih, gbhh, W2, b2, q);
    slstm_kernel<<<dim3(2), dim3(512), 0, stream>>>(
        q, pWih, pWhh, pbih, pbhh, vWih, vWhh, vbih, vbhh, (float*)d_out, U, N);
}